// Round 1
// baseline (1741.903 us; speedup 1.0000x reference)
//
#include <hip/hip_runtime.h>

#define B_ 8
#define H_ 96
#define W_ 96
#define C_ 384
#define SH_ 24
#define SW_ 24
#define M_ 576
#define N_ 9216
#define TEMP_ 0.01f

// ------------------------------------------------------------------
// K1: init centroids (4x4 block mean) + |s|^2 per superpixel
// grid: B_*M_ blocks, 384 threads (thread = channel)
// ------------------------------------------------------------------
__global__ __launch_bounds__(384) void k_init(const float* __restrict__ pix,
                                              float* __restrict__ sp,
                                              float* __restrict__ sq) {
  int bm = blockIdx.x;
  int b = bm / M_, m = bm % M_;
  int mh = m / SW_, mw = m % SW_;
  int c = threadIdx.x;
  const float* base = pix + (((size_t)(b * H_ + mh * 4)) * W_ + mw * 4) * C_ + c;
  float s = 0.f;
#pragma unroll
  for (int i = 0; i < 4; i++)
#pragma unroll
    for (int j = 0; j < 4; j++)
      s += base[(size_t)(i * W_ + j) * C_];
  s *= 0.0625f;
  sp[((size_t)(b * M_) + m) * C_ + c] = s;
  float q = s * s;
#pragma unroll
  for (int off = 32; off > 0; off >>= 1) q += __shfl_down(q, off);
  __shared__ float red[6];
  if ((c & 63) == 0) red[c >> 6] = q;
  __syncthreads();
  if (c == 0) sq[b * M_ + m] = red[0] + red[1] + red[2] + red[3] + red[4] + red[5];
}

// ------------------------------------------------------------------
// K3: affinities. One thread = one pixel. Workgroup = 8 label blocks
// (one label row third: lh fixed, lw0..lw0+7), 128 threads.
// Candidate window union: 5 rows x 12 cols = 60 centroids staged in
// LDS (f32, stride 196 to kill bank conflicts, 16B aligned), K split
// into two halves of 192 channels to keep LDS at ~47KB (3 wg/CU).
// logit = TEMP*(2*dot - |s|^2)  (|p|^2 cancels in softmax)
// aff layout: [B*N][25], slot k=(dh+2)*5+(dw+2) -> m=(lh+dh, lw+dw)
// ------------------------------------------------------------------
__global__ __launch_bounds__(128) void k_aff(const float* __restrict__ pix,
                                             const float* __restrict__ sp,
                                             const float* __restrict__ sq,
                                             float* __restrict__ aff) {
  int wg = blockIdx.x;
  int b = wg / 72, r = wg % 72;
  int lh = r / 3, lw0 = (r % 3) * 8;
  __shared__ float sL[60 * 196];
  __shared__ float sqL[60];
  int t = threadIdx.x;
  for (int e = t; e < 60; e += 128) {
    int mh = lh - 2 + e / 12, mw = lw0 - 2 + e % 12;
    sqL[e] = (mh >= 0 && mh < SH_ && mw >= 0 && mw < SW_) ? sq[b * M_ + mh * SW_ + mw] : 0.f;
  }
  int i = t >> 4, j = t & 15;
  int lw = lw0 + i;
  int h = lh * 4 + (j >> 2), w = lw * 4 + (j & 3);
  const float* prow = pix + (((size_t)(b * H_ + h)) * W_ + w) * C_;
  float acc[25];
#pragma unroll
  for (int k = 0; k < 25; k++) acc[k] = 0.f;

  for (int half = 0; half < 2; half++) {
    __syncthreads();
    int cbase = half * 192;
    for (int e = t; e < 60 * 48; e += 128) {
      int u = e / 48, c4 = e % 48;
      int mh = lh - 2 + u / 12, mw = lw0 - 2 + u % 12;
      float4 v = make_float4(0.f, 0.f, 0.f, 0.f);
      if (mh >= 0 && mh < SH_ && mw >= 0 && mw < SW_)
        v = *(const float4*)(sp + ((size_t)(b * M_ + mh * SW_ + mw)) * C_ + cbase + c4 * 4);
      *(float4*)&sL[u * 196 + c4 * 4] = v;
    }
    __syncthreads();
    for (int c0 = 0; c0 < 192; c0 += 8) {
      float4 pa = *(const float4*)(prow + cbase + c0);
      float4 pb = *(const float4*)(prow + cbase + c0 + 4);
#pragma unroll
      for (int dh = 0; dh < 5; dh++) {
#pragma unroll
        for (int dw = 0; dw < 5; dw++) {
          const float* srow = &sL[(dh * 12 + i + dw) * 196 + c0];
          float4 sa = *(const float4*)srow;
          float4 sb = *(const float4*)(srow + 4);
          float tsum = fmaf(pa.x, sa.x, fmaf(pa.y, sa.y, fmaf(pa.z, sa.z, pa.w * sa.w)));
          tsum = fmaf(pb.x, sb.x, fmaf(pb.y, sb.y, fmaf(pb.z, sb.z, fmaf(pb.w, sb.w, tsum))));
          acc[dh * 5 + dw] += tsum;
        }
      }
    }
  }
  // epilogue: masked softmax over 25 slots
  float lg[25];
  float mx = -3e38f;
#pragma unroll
  for (int dh = 0; dh < 5; dh++) {
#pragma unroll
    for (int dw = 0; dw < 5; dw++) {
      int k = dh * 5 + dw;
      int mh = lh - 2 + dh, mw = lw - 2 + dw;
      int u = dh * 12 + i + dw;
      bool valid = (mh >= 0) && (mh < SH_) && (mw >= 0) && (mw < SW_);
      float l = valid ? (TEMP_ * (2.f * acc[k] - sqL[u])) : -3e38f;
      lg[k] = l;
      mx = fmaxf(mx, l);
    }
  }
  float z = 0.f;
#pragma unroll
  for (int k = 0; k < 25; k++) {
    float e = __expf(lg[k] - mx);
    lg[k] = e;
    z += e;
  }
  float inv = 1.f / z;
  float* arow = aff + ((size_t)(b * N_) + h * W_ + w) * 25;
#pragma unroll
  for (int k = 0; k < 25; k++) arow[k] = lg[k] * inv;
}

// ------------------------------------------------------------------
// K4: scatter aggregation. Workgroup = (b, label row lh, half) with
// 12 label cols; 384 threads (thread = channel). Register
// accumulators acc[5 dh][16 mw_local], lwl loop fully unrolled so all
// indices are compile-time (avoids scratch). aff reads are
// block-uniform -> scalar loads. atomicAdd into global accumulator.
// ------------------------------------------------------------------
__global__ __launch_bounds__(384) void k_scatter(const float* __restrict__ pix,
                                                 const float* __restrict__ aff,
                                                 float* __restrict__ accum) {
  int wg = blockIdx.x;
  int b = wg / 48, r = wg % 48;
  int lh = r / 2, lw0 = (r % 2) * 12;
  int c = threadIdx.x;
  float acc[5][16];
#pragma unroll
  for (int a = 0; a < 5; a++)
#pragma unroll
    for (int w2 = 0; w2 < 16; w2++) acc[a][w2] = 0.f;
#pragma unroll
  for (int lwl = 0; lwl < 12; lwl++) {
    int lw = lw0 + lwl;
#pragma unroll 4
    for (int jj = 0; jj < 16; jj++) {
      int h = lh * 4 + (jj >> 2);
      int w = lw * 4 + (jj & 3);
      const float* ar = aff + ((size_t)(b * N_) + h * W_ + w) * 25;
      float val = pix[(((size_t)(b * H_) + h) * W_ + w) * C_ + c];
#pragma unroll
      for (int dh = 0; dh < 5; dh++)
#pragma unroll
        for (int dw = 0; dw < 5; dw++)
          acc[dh][lwl + dw] = fmaf(ar[dh * 5 + dw], val, acc[dh][lwl + dw]);
    }
  }
#pragma unroll
  for (int dh = 0; dh < 5; dh++) {
    int mh = lh - 2 + dh;
    if (mh < 0 || mh >= SH_) continue;
#pragma unroll
    for (int wi = 0; wi < 16; wi++) {
      int mw = lw0 - 2 + wi;
      if (mw < 0 || mw >= SW_) continue;
      atomicAdd(&accum[((size_t)(b * M_) + mh * SW_ + mw) * C_ + c], acc[dh][wi]);
    }
  }
}

// ------------------------------------------------------------------
// K6: finalize iteration: denom = sum of aff over window (gather),
// sp = accum/denom, sq = |s|^2. Block = (b,m), 384 threads.
// ------------------------------------------------------------------
__global__ __launch_bounds__(384) void k_fin(const float* __restrict__ aff,
                                             const float* __restrict__ accum,
                                             float* __restrict__ sp,
                                             float* __restrict__ sq) {
  int bm = blockIdx.x;
  int b = bm / M_, m = bm % M_;
  int mh = m / SW_, mw = m % SW_;
  int t = threadIdx.x;
  int h0 = (mh - 2) * 4; if (h0 < 0) h0 = 0;
  int h1 = (mh + 3) * 4; if (h1 > H_) h1 = H_;
  int w0 = (mw - 2) * 4; if (w0 < 0) w0 = 0;
  int w1 = (mw + 3) * 4; if (w1 > W_) w1 = W_;
  int nw = w1 - w0;
  int np = (h1 - h0) * nw;
  float d = 0.f;
  for (int e = t; e < np; e += 384) {
    int hh = h0 + e / nw, ww = w0 + e % nw;
    int k = (mh - (hh >> 2) + 2) * 5 + (mw - (ww >> 2) + 2);
    d += aff[((size_t)(b * N_) + hh * W_ + ww) * 25 + k];
  }
  __shared__ float red[6];
#pragma unroll
  for (int off = 32; off > 0; off >>= 1) d += __shfl_down(d, off);
  if ((t & 63) == 0) red[t >> 6] = d;
  __syncthreads();
  float denom = fmaxf(red[0] + red[1] + red[2] + red[3] + red[4] + red[5], 1e-16f);
  size_t idx = ((size_t)(b * M_) + m) * C_ + t;
  float sv = accum[idx] / denom;
  sp[idx] = sv;
  float q = sv * sv;
#pragma unroll
  for (int off = 32; off > 0; off >>= 1) q += __shfl_down(q, off);
  __syncthreads();
  if ((t & 63) == 0) red[t >> 6] = q;
  __syncthreads();
  if (t == 0) sq[b * M_ + m] = red[0] + red[1] + red[2] + red[3] + red[4] + red[5];
}

// ------------------------------------------------------------------
// K7: final unmasked argmin over all 576 superpixels (exact f32).
// argmin_m (|s_m|^2 - 2 s_m . p)  (|p|^2 cancels)
// Workgroup: 256 threads, 128 pixels; thread tile 8px x 4cand;
// cand chunks of 64, K chunks of 32 staged in LDS with XOR swizzle
// on 16B blocks to avoid bank conflicts. First-min-index tie-break.
// ------------------------------------------------------------------
__global__ __launch_bounds__(256) void k_argmin(const float* __restrict__ pix,
                                                const float* __restrict__ sp,
                                                const float* __restrict__ sq,
                                                float* __restrict__ lab) {
  int wg = blockIdx.x;
  int b = wg / 72;
  int px0 = (wg % 72) * 128;
  __shared__ float pT[128 * 36];
  __shared__ float sT[64 * 36];
  __shared__ float sqT[64];
  int t = threadIdx.x;
  int pxg = t >> 4, cg = t & 15;
  float best[8];
  int bidx[8];
#pragma unroll
  for (int x = 0; x < 8; x++) { best[x] = 3.4e38f; bidx[x] = 0; }

  for (int m0 = 0; m0 < M_; m0 += 64) {
    __syncthreads();
    if (t < 64) sqT[t] = sq[b * M_ + m0 + t];
    float acc[8][4];
#pragma unroll
    for (int x = 0; x < 8; x++)
#pragma unroll
      for (int y = 0; y < 4; y++) acc[x][y] = 0.f;

    for (int k0 = 0; k0 < C_; k0 += 32) {
      __syncthreads();
      {
        int row = t >> 1, o = (t & 1) * 16;
        const float* src = pix + ((size_t)(b * N_) + px0 + row) * C_ + k0 + o;
        int sw = (row >> 3) & 7;
#pragma unroll
        for (int jj = 0; jj < 4; jj++) {
          float4 v = *(const float4*)(src + jj * 4);
          int ob = (o >> 2) + jj;
          *(float4*)&pT[row * 36 + ((ob ^ sw) << 2)] = v;
        }
      }
      if (t < 128) {
        int row = t >> 1, o = (t & 1) * 16;
        const float* src = sp + ((size_t)(b * M_) + m0 + row) * C_ + k0 + o;
        int sw = (row >> 2) & 7;
#pragma unroll
        for (int jj = 0; jj < 4; jj++) {
          float4 v = *(const float4*)(src + jj * 4);
          int ob = (o >> 2) + jj;
          *(float4*)&sT[row * 36 + ((ob ^ sw) << 2)] = v;
        }
      }
      __syncthreads();
#pragma unroll
      for (int q = 0; q < 8; q++) {
        float4 bb[4];
#pragma unroll
        for (int y = 0; y < 4; y++) {
          int row = (cg << 2) + y;
          bb[y] = *(const float4*)&sT[row * 36 + ((q ^ (cg & 7)) << 2)];
        }
#pragma unroll
        for (int x = 0; x < 8; x++) {
          int row = (pxg << 3) + x;
          float4 av = *(const float4*)&pT[row * 36 + ((q ^ (pxg & 7)) << 2)];
#pragma unroll
          for (int y = 0; y < 4; y++) {
            acc[x][y] = fmaf(av.x, bb[y].x,
                        fmaf(av.y, bb[y].y,
                        fmaf(av.z, bb[y].z,
                        fmaf(av.w, bb[y].w, acc[x][y]))));
          }
        }
      }
    }
    // fold this candidate chunk into running best (ascending index order)
#pragma unroll
    for (int y = 0; y < 4; y++) {
      int mi = m0 + (cg << 2) + y;
      float dq = sqT[(cg << 2) + y];
#pragma unroll
      for (int x = 0; x < 8; x++) {
        float dist = dq - 2.f * acc[x][y];
        if (dist < best[x]) { best[x] = dist; bidx[x] = mi; }
      }
    }
  }
  // reduce across the 16 cand-group lanes sharing each pixel group
#pragma unroll
  for (int off = 1; off < 16; off <<= 1) {
#pragma unroll
    for (int x = 0; x < 8; x++) {
      float ov = __shfl_xor(best[x], off, 16);
      int oi = __shfl_xor(bidx[x], off, 16);
      if (ov < best[x] || (ov == best[x] && oi < bidx[x])) { best[x] = ov; bidx[x] = oi; }
    }
  }
  if (cg == 0) {
#pragma unroll
    for (int x = 0; x < 8; x++)
      lab[(size_t)(b * N_) + px0 + (pxg << 3) + x] = (float)bidx[x];
  }
}

// ------------------------------------------------------------------
// K8: copy sp (B,M,C) -> out features (identical flat layout)
// ------------------------------------------------------------------
__global__ __launch_bounds__(256) void k_copy(const float4* __restrict__ src,
                                              float4* __restrict__ dst) {
  int i = blockIdx.x * 256 + threadIdx.x;
  dst[i] = src[i];
}

// ------------------------------------------------------------------
extern "C" void kernel_launch(void* const* d_in, const int* in_sizes, int n_in,
                              void* d_out, int out_size, void* d_ws, size_t ws_size,
                              hipStream_t stream) {
  const float* pix = (const float*)d_in[0];
  float* out = (float*)d_out;
  char* ws = (char*)d_ws;
  float* sp    = (float*)(ws);               // 7,077,888 B
  float* accum = (float*)(ws + 7077888);     // 7,077,888 B
  float* aff   = (float*)(ws + 14155776);    // 7,372,800 B
  float* sq    = (float*)(ws + 21528576);    //    18,432 B

  k_init<<<B_ * M_, 384, 0, stream>>>(pix, sp, sq);
  for (int it = 0; it < 5; it++) {
    hipMemsetAsync(accum, 0, 7077888, stream);
    k_aff<<<576, 128, 0, stream>>>(pix, sp, sq, aff);
    k_scatter<<<384, 384, 0, stream>>>(pix, aff, accum);
    k_fin<<<B_ * M_, 384, 0, stream>>>(aff, accum, sp, sq);
  }
  k_argmin<<<576, 256, 0, stream>>>(pix, sp, sq, out + 1769472);
  k_copy<<<1728, 256, 0, stream>>>((const float4*)sp, (float4*)out);
}